// Round 5
// baseline (1135.081 us; speedup 1.0000x reference)
//
#include <hip/hip_runtime.h>

#define KMAX 25            // unrolled edges per thread in count/scatter
#define CTH  256           // threads per count/scatter block

__device__ __forceinline__ unsigned short f2bf(float x) {   // RNE
    unsigned u = __float_as_uint(x);
    u += 0x7FFF + ((u >> 16) & 1);
    return (unsigned short)(u >> 16);
}

// ---------------- count events per (bucket, block) ----------------
__global__ __launch_bounds__(CTH) void k_count(const int* __restrict__ src,
        const int* __restrict__ dst, int* __restrict__ tab,
        int E, int NBK, int NBC) {
    __shared__ int cS[512], cD[512];
    const int t = threadIdx.x;
    for (int i = t; i < 512; i += CTH) { cS[i] = 0; cD[i] = 0; }
    __syncthreads();
    const int e0 = blockIdx.x * (KMAX * CTH);
    int e1 = e0 + KMAX * CTH; if (e1 > E) e1 = E;
    for (int e = e0 + t; e < e1; e += CTH) {
        atomicAdd(&cS[src[e] >> 8], 1);
        atomicAdd(&cD[dst[e] >> 8], 1);
    }
    __syncthreads();
    for (int b = t; b < NBK; b += CTH) {
        tab[(size_t)b * NBC + blockIdx.x]         = cS[b];
        tab[(size_t)(NBK + b) * NBC + blockIdx.x] = cD[b];
    }
}

// ---------------- single-block exclusive scan of the whole table ----------------
__global__ __launch_bounds__(512) void k_scan(int* __restrict__ tab, int Ntab) {
    __shared__ int part[512];
    const int t = threadIdx.x;
    const int chunk = (Ntab + 511) / 512;
    int i0 = t * chunk; int i1 = i0 + chunk; if (i1 > Ntab) i1 = Ntab; if (i0 > Ntab) i0 = Ntab;
    int s = 0;
    for (int i = i0; i < i1; ++i) s += tab[i];
    part[t] = s;
    __syncthreads();
    for (int off = 1; off < 512; off <<= 1) {
        int v = (t >= off) ? part[t - off] : 0;
        __syncthreads();
        part[t] += v;
        __syncthreads();
    }
    int run = part[t] - s;   // exclusive base for this thread's chunk
    for (int i = i0; i < i1; ++i) { int v = tab[i]; tab[i] = run; run += v; }
    if (t == 511) tab[Ntab] = run;   // sentinel = grand total (2E)
}

// ---------------- scatter: src-events (1B) and dst-events (packed u32) ----------------
__global__ __launch_bounds__(CTH) void k_scatter(const int* __restrict__ src,
        const int* __restrict__ dst, const int* __restrict__ tab,
        unsigned char* __restrict__ srecs, unsigned* __restrict__ drecs,
        int E, int NBK, int NBC) {
    __shared__ int cS[512], cD[512];
    __shared__ int bS[512], bD[512];
    const int t = threadIdx.x;
    for (int i = t; i < 512; i += CTH) { cS[i] = 0; cD[i] = 0; }
    __syncthreads();
    const int e0 = blockIdx.x * (KMAX * CTH);
    int e1 = e0 + KMAX * CTH; if (e1 > E) e1 = E;
    unsigned short rS[KMAX], rD[KMAX];
#pragma unroll
    for (int k = 0; k < KMAX; ++k) {
        int e = e0 + k * CTH + t;
        if (e < e1) {
            rS[k] = (unsigned short)atomicAdd(&cS[src[e] >> 8], 1);
            rD[k] = (unsigned short)atomicAdd(&cD[dst[e] >> 8], 1);
        }
    }
    __syncthreads();
    for (int b = t; b < NBK; b += CTH) {
        bS[b] = tab[(size_t)b * NBC + blockIdx.x];
        bD[b] = tab[(size_t)(NBK + b) * NBC + blockIdx.x] - E;
    }
    __syncthreads();
#pragma unroll
    for (int k = 0; k < KMAX; ++k) {
        int e = e0 + k * CTH + t;
        if (e < e1) {
            int s = src[e], d = dst[e];
            srecs[bS[s >> 8] + rS[k]] = (unsigned char)(s & 255);
            drecs[bD[d >> 8] + rD[k]] = ((unsigned)s << 8) | (unsigned)(d & 255);
        }
    }
}

// ---------------- per-bucket degree counts -> ns, nd, gcnt ----------------
__global__ __launch_bounds__(256) void k_degrees(const unsigned char* __restrict__ srecs,
        const unsigned* __restrict__ drecs, const int* __restrict__ tab,
        const int* __restrict__ seg, float* __restrict__ ns, float* __restrict__ nd,
        int* __restrict__ gcnt, int N, int NBK, int NBC, int E) {
    __shared__ int oc[256], ic[256];
    const int b = blockIdx.x, t = threadIdx.x;
    oc[t] = 0; ic[t] = 0;
    __syncthreads();
    const int sA0 = tab[(size_t)b * NBC];
    const int sA1 = tab[(size_t)(b + 1) * NBC];
    const int dA0 = tab[(size_t)(NBK + b) * NBC] - E;
    const int dA1 = tab[(size_t)(NBK + b + 1) * NBC] - E;
    for (int i = sA0 + t; i < sA1; i += 256) atomicAdd(&oc[srecs[i]], 1);
    for (int i = dA0 + t; i < dA1; i += 256) atomicAdd(&ic[drecs[i] & 255], 1);
    __syncthreads();
    const int node = (b << 8) + t;
    if (node < N) {
        ns[node] = rsqrtf(fmaxf((float)oc[t], 1.f));
        nd[node] = rsqrtf(fmaxf((float)ic[t], 1.f));
        atomicAdd(&gcnt[seg[node]], 1);
    }
}

// ---------------- projection: Hb[n][c] = bf16((X[n,:].W[:,c]) * ns[n]) ----------------
__global__ __launch_bounds__(256) void k_gemm(const float* __restrict__ X,
                                              const float* __restrict__ W,
                                              const float* __restrict__ ns,
                                              unsigned short* __restrict__ Hb, int N) {
    __shared__ __align__(16) float lx[256 * 36];
    __shared__ __align__(16) float lw[16 * 260];
    const int t = threadIdx.x;
    const int node0 = blockIdx.x * 256;

    for (int i = t; i < 256 * 16; i += 256) {
        int k = i >> 4, c = i & 15;
        lw[c * 260 + k] = W[i];
    }

    const int m  = t >> 2;
    const int cb = (t & 3) * 4;

    float4 acc[4][4];
#pragma unroll
    for (int j = 0; j < 4; ++j)
#pragma unroll
        for (int ci = 0; ci < 4; ++ci) acc[j][ci] = float4{0.f, 0.f, 0.f, 0.f};

    for (int kt = 0; kt < 8; ++kt) {
        const int k0 = kt * 32;
        __syncthreads();
#pragma unroll
        for (int i = 0; i < 8; ++i) {
            int f = t + 256 * i;
            int row = f >> 3, c4 = f & 7;
            float4 v = float4{0.f, 0.f, 0.f, 0.f};
            int node = node0 + row;
            if (node < N) v = *(const float4*)&X[(size_t)node * 256 + k0 + c4 * 4];
            *(float4*)&lx[row * 36 + c4 * 4] = v;
        }
        __syncthreads();
#pragma unroll
        for (int kk = 0; kk < 32; kk += 4) {
            float4 wv[4], xv[4];
#pragma unroll
            for (int ci = 0; ci < 4; ++ci)
                wv[ci] = *(const float4*)&lw[(cb + ci) * 260 + k0 + kk];
#pragma unroll
            for (int j = 0; j < 4; ++j)
                xv[j] = *(const float4*)&lx[(m + 64 * j) * 36 + kk];
#pragma unroll
            for (int j = 0; j < 4; ++j)
#pragma unroll
                for (int ci = 0; ci < 4; ++ci) {
                    acc[j][ci].x += xv[j].x * wv[ci].x;
                    acc[j][ci].y += xv[j].y * wv[ci].y;
                    acc[j][ci].z += xv[j].z * wv[ci].z;
                    acc[j][ci].w += xv[j].w * wv[ci].w;
                }
        }
    }

#pragma unroll
    for (int j = 0; j < 4; ++j) {
        int node = node0 + m + 64 * j;
        if (node < N) {
            float norm = ns[node];
            ushort4 o;
            float s0 = acc[j][0].x + acc[j][0].y + acc[j][0].z + acc[j][0].w;
            float s1 = acc[j][1].x + acc[j][1].y + acc[j][1].z + acc[j][1].w;
            float s2 = acc[j][2].x + acc[j][2].y + acc[j][2].z + acc[j][2].w;
            float s3 = acc[j][3].x + acc[j][3].y + acc[j][3].z + acc[j][3].w;
            o.x = f2bf(s0 * norm); o.y = f2bf(s1 * norm);
            o.z = f2bf(s2 * norm); o.w = f2bf(s3 * norm);
            *(ushort4*)&Hb[(size_t)node * 16 + cb] = o;
        }
    }
}

// ---------------- per-bucket edge accumulation in REGISTERS ----------------
// 2 blocks per bucket; slot gi in {0,1,2} -> 48 fp32 register accumulators,
// cndmask weights (no atomics). Rare span>3 -> LDS hist; span>16 -> global.
__global__ __launch_bounds__(256) void k_gaccum(const unsigned* __restrict__ drecs,
        const int* __restrict__ tab, const int* __restrict__ seg,
        const float* __restrict__ nd, const unsigned short* __restrict__ Hb,
        float* __restrict__ outagg, int N, int NBK, int NBC, int E, int G) {
    __shared__ float lnd[256];
    __shared__ int   lgi[256];
    __shared__ float lhist[256];      // [16 slots][16 classes], rows 3..15 used
    __shared__ float wred[4 * 48];
    const int b = blockIdx.x >> 1, half = blockIdx.x & 1;
    const int t = threadIdx.x;
    const int node0 = b << 8;
    const int gf = seg[node0];
    lhist[t] = 0.f;
    const int node = node0 + t;
    if (node < N) {
        lnd[t] = nd[node];
        lgi[t] = seg[node] - gf;
    }
    __syncthreads();
    const int dA0 = tab[(size_t)(NBK + b) * NBC] - E;
    const int dA1 = tab[(size_t)(NBK + b + 1) * NBC] - E;
    const int mid = dA0 + ((dA1 - dA0) >> 1);
    const int i0 = half ? mid : dA0;
    const int i1 = half ? dA1 : mid;

    float a0[16], a1[16], a2[16];
#pragma unroll
    for (int j = 0; j < 16; ++j) { a0[j] = 0.f; a1[j] = 0.f; a2[j] = 0.f; }

    for (int i = i0 + t; i < i1; i += 256) {
        const unsigned r = drecs[i];
        const int dlow = r & 255;
        const int s = (int)(r >> 8);
        const float w = lnd[dlow];
        const int gi = lgi[dlow];
        const uint4* hp = (const uint4*)(Hb + (size_t)s * 16);
        const uint4 h0 = hp[0];
        const uint4 h1 = hp[1];
        if (gi < 3) {
            const float w0 = (gi == 0) ? w : 0.f;
            const float w1 = (gi == 1) ? w : 0.f;
            const float w2 = (gi == 2) ? w : 0.f;
#define ACC2(u, j0) { \
            float vlo = __uint_as_float((u) << 16); \
            float vhi = __uint_as_float((u) & 0xFFFF0000u); \
            a0[j0] += vlo * w0; a1[j0] += vlo * w1; a2[j0] += vlo * w2; \
            a0[j0+1] += vhi * w0; a1[j0+1] += vhi * w1; a2[j0+1] += vhi * w2; }
            ACC2(h0.x, 0) ACC2(h0.y, 2) ACC2(h0.z, 4) ACC2(h0.w, 6)
            ACC2(h1.x, 8) ACC2(h1.y, 10) ACC2(h1.z, 12) ACC2(h1.w, 14)
#undef ACC2
        } else {
            const unsigned hw[8] = {h0.x, h0.y, h0.z, h0.w, h1.x, h1.y, h1.z, h1.w};
            if (gi < 16) {
#pragma unroll
                for (int q = 0; q < 8; ++q) {
                    atomicAdd(&lhist[gi * 16 + 2 * q],     __uint_as_float(hw[q] << 16) * w);
                    atomicAdd(&lhist[gi * 16 + 2 * q + 1], __uint_as_float(hw[q] & 0xFFFF0000u) * w);
                }
            } else if (gf + gi < G) {   // astronomically rare
#pragma unroll
                for (int q = 0; q < 8; ++q) {
                    unsafeAtomicAdd(&outagg[(gf + gi) * 16 + 2 * q],     __uint_as_float(hw[q] << 16) * w);
                    unsafeAtomicAdd(&outagg[(gf + gi) * 16 + 2 * q + 1], __uint_as_float(hw[q] & 0xFFFF0000u) * w);
                }
            }
        }
    }

    // wave shuffle-reduce the 48 register sums
#pragma unroll
    for (int j = 0; j < 16; ++j) {
#pragma unroll
        for (int off = 32; off > 0; off >>= 1) {
            a0[j] += __shfl_down(a0[j], off, 64);
            a1[j] += __shfl_down(a1[j], off, 64);
            a2[j] += __shfl_down(a2[j], off, 64);
        }
    }
    const int wid = t >> 6, lane = t & 63;
    if (lane == 0) {
#pragma unroll
        for (int j = 0; j < 16; ++j) {
            wred[wid * 48 + j]      = a0[j];
            wred[wid * 48 + 16 + j] = a1[j];
            wred[wid * 48 + 32 + j] = a2[j];
        }
    }
    __syncthreads();
    if (t < 48) {
        const float v = wred[t] + wred[48 + t] + wred[96 + t] + wred[144 + t];
        const int g = gf + t / 16;
        if (v != 0.f && g < G) unsafeAtomicAdd(&outagg[g * 16 + (t & 15)], v);
    } else {
        const float v = lhist[t];       // rows 3..15 fallback
        const int g = gf + t / 16;
        if (v != 0.f && g < G) unsafeAtomicAdd(&outagg[g * 16 + (t & 15)], v);
    }
}

// ---------------- final: out = outagg / max(gcnt,1) + bias ----------------
__global__ void k_final(const float* __restrict__ outagg, const int* __restrict__ gcnt,
                        const float* __restrict__ bias, float* __restrict__ out, int G) {
    int i = blockIdx.x * 256 + threadIdx.x;
    if (i < G * 16)
        out[i] = outagg[i] / fmaxf((float)gcnt[i >> 4], 1.f) + bias[i & 15];
}

extern "C" void kernel_launch(void* const* d_in, const int* in_sizes, int n_in,
                              void* d_out, int out_size, void* d_ws, size_t ws_size,
                              hipStream_t stream) {
    const float* X  = (const float*)d_in[0];
    const float* W  = (const float*)d_in[1];
    const float* bb = (const float*)d_in[2];
    const int* esrc = (const int*)d_in[3];
    const int* edst = (const int*)d_in[4];
    const int* seg  = (const int*)d_in[5];
    const int N = in_sizes[5];                 // 100000
    const int E = in_sizes[3];                 // 3200000
    const int G = out_size / 16;               // 256
    const int NBK = (N + 255) >> 8;            // 391 (<=512 required)
    const int NBC = (E + KMAX * CTH - 1) / (KMAX * CTH);   // 500
    const size_t tabN = (size_t)2 * NBK * NBC + 1;

    // ws layout (~18.4 MB; srecs/Hb aliased — srecs dead before gemm writes Hb)
    unsigned* drecs = (unsigned*)d_ws;                       // E u32 (12.8 MB)
    int* tab        = (int*)(drecs + (size_t)E);             // tabN ints (1.56 MB)
    float* ns       = (float*)(tab + tabN);                  // N
    float* nd       = ns + N;                                // N
    float* outagg   = nd + N;                                // G*16  <- memset
    int* gcnt       = (int*)(outagg + (size_t)G * 16);       // G     <- memset
    unsigned char* srecs = (unsigned char*)(gcnt + G);       // E bytes \ aliased
    unsigned short* Hb   = (unsigned short*)srecs;           // N*16   / region

    hipMemsetAsync(outagg, 0, (size_t)G * 16 * 4 + (size_t)G * 4, stream);

    k_count  <<<NBC, CTH, 0, stream>>>(esrc, edst, tab, E, NBK, NBC);
    k_scan   <<<1, 512, 0, stream>>>(tab, (int)(tabN - 1));
    k_scatter<<<NBC, CTH, 0, stream>>>(esrc, edst, tab, srecs, drecs, E, NBK, NBC);
    k_degrees<<<NBK, 256, 0, stream>>>(srecs, drecs, tab, seg, ns, nd, gcnt, N, NBK, NBC, E);
    k_gemm   <<<(N + 255) / 256, 256, 0, stream>>>(X, W, ns, Hb, N);
    k_gaccum <<<NBK * 2, 256, 0, stream>>>(drecs, tab, seg, nd, Hb, outagg, N, NBK, NBC, E, G);
    k_final  <<<(G * 16 + 255) / 256, 256, 0, stream>>>(outagg, gcnt, bb, (float*)d_out, G);
}

// Round 6
// 521.349 us; speedup vs baseline: 2.1772x; 2.1772x over previous
//
#include <hip/hip_runtime.h>

#define KMAX 25            // unrolled edges per thread in count/scatter
#define CTH  256           // threads per count/scatter block

__device__ __forceinline__ unsigned short f2bf(float x) {   // RNE
    unsigned u = __float_as_uint(x);
    u += 0x7FFF + ((u >> 16) & 1);
    return (unsigned short)(u >> 16);
}

// ---------------- count events per (bucket, block) ----------------
__global__ __launch_bounds__(CTH) void k_count(const int* __restrict__ src,
        const int* __restrict__ dst, int* __restrict__ tab,
        int E, int NBK, int NBC) {
    __shared__ int cS[512], cD[512];
    const int t = threadIdx.x;
    for (int i = t; i < 512; i += CTH) { cS[i] = 0; cD[i] = 0; }
    __syncthreads();
    const int e0 = blockIdx.x * (KMAX * CTH);
    int e1 = e0 + KMAX * CTH; if (e1 > E) e1 = E;
    for (int e = e0 + t; e < e1; e += CTH) {
        atomicAdd(&cS[src[e] >> 8], 1);
        atomicAdd(&cD[dst[e] >> 8], 1);
    }
    __syncthreads();
    for (int b = t; b < NBK; b += CTH) {
        tab[(size_t)b * NBC + blockIdx.x]         = cS[b];
        tab[(size_t)(NBK + b) * NBC + blockIdx.x] = cD[b];
    }
}

// ---------------- hierarchical exclusive scan (3 phases) ----------------
// A: per-block (2048-entry) sums
__global__ __launch_bounds__(256) void k_scanA(const int* __restrict__ tab,
                                               int* __restrict__ bsum, int Ntab) {
    __shared__ int red[256];
    const int t = threadIdx.x;
    const int base = blockIdx.x * 2048 + t * 8;
    int s = 0;
#pragma unroll
    for (int k = 0; k < 8; ++k) { int i = base + k; if (i < Ntab) s += tab[i]; }
    red[t] = s; __syncthreads();
    for (int off = 128; off > 0; off >>= 1) {
        if (t < off) red[t] += red[t + off];
        __syncthreads();
    }
    if (t == 0) bsum[blockIdx.x] = red[0];
}

// B: single-block exclusive scan of the block sums (chunked, any NB)
__global__ __launch_bounds__(256) void k_scanB(int* __restrict__ bsum, int NB) {
    __shared__ int sc[256];
    __shared__ int carry;
    const int t = threadIdx.x;
    if (t == 0) carry = 0;
    __syncthreads();
    for (int base = 0; base < NB; base += 256) {
        const int i = base + t;
        const int v = (i < NB) ? bsum[i] : 0;
        sc[t] = v; __syncthreads();
        for (int off = 1; off < 256; off <<= 1) {
            int add = (t >= off) ? sc[t - off] : 0;
            __syncthreads();
            sc[t] += add;
            __syncthreads();
        }
        if (i < NB) bsum[i] = carry + sc[t] - v;   // exclusive
        __syncthreads();
        if (t == 255) carry += sc[255];
        __syncthreads();
    }
}

// C: per-block exclusive rescan + base; owner of last element writes sentinel
__global__ __launch_bounds__(256) void k_scanC(int* __restrict__ tab,
                                               const int* __restrict__ bsum, int Ntab) {
    __shared__ int sc[256];
    const int t = threadIdx.x;
    const int base = blockIdx.x * 2048 + t * 8;
    int v[8]; int s = 0;
#pragma unroll
    for (int k = 0; k < 8; ++k) { int i = base + k; v[k] = (i < Ntab) ? tab[i] : 0; s += v[k]; }
    sc[t] = s; __syncthreads();
    for (int off = 1; off < 256; off <<= 1) {
        int add = (t >= off) ? sc[t - off] : 0;
        __syncthreads();
        sc[t] += add;
        __syncthreads();
    }
    int run = bsum[blockIdx.x] + sc[t] - s;
#pragma unroll
    for (int k = 0; k < 8; ++k) {
        int i = base + k;
        if (i < Ntab) { tab[i] = run; run += v[k]; }
    }
    if (base < Ntab && Ntab <= base + 8) tab[Ntab] = run;   // sentinel = 2E
}

// ---------------- scatter: src-events (1B) and dst-events (packed u32) ----------------
__global__ __launch_bounds__(CTH) void k_scatter(const int* __restrict__ src,
        const int* __restrict__ dst, const int* __restrict__ tab,
        unsigned char* __restrict__ srecs, unsigned* __restrict__ drecs,
        int E, int NBK, int NBC) {
    __shared__ int cS[512], cD[512];
    __shared__ int bS[512], bD[512];
    const int t = threadIdx.x;
    for (int i = t; i < 512; i += CTH) { cS[i] = 0; cD[i] = 0; }
    __syncthreads();
    const int e0 = blockIdx.x * (KMAX * CTH);
    int e1 = e0 + KMAX * CTH; if (e1 > E) e1 = E;
    unsigned short rS[KMAX], rD[KMAX];
#pragma unroll
    for (int k = 0; k < KMAX; ++k) {
        int e = e0 + k * CTH + t;
        if (e < e1) {
            rS[k] = (unsigned short)atomicAdd(&cS[src[e] >> 8], 1);
            rD[k] = (unsigned short)atomicAdd(&cD[dst[e] >> 8], 1);
        }
    }
    __syncthreads();
    for (int b = t; b < NBK; b += CTH) {
        bS[b] = tab[(size_t)b * NBC + blockIdx.x];
        bD[b] = tab[(size_t)(NBK + b) * NBC + blockIdx.x] - E;
    }
    __syncthreads();
#pragma unroll
    for (int k = 0; k < KMAX; ++k) {
        int e = e0 + k * CTH + t;
        if (e < e1) {
            int s = src[e], d = dst[e];
            srecs[bS[s >> 8] + rS[k]] = (unsigned char)(s & 255);
            drecs[bD[d >> 8] + rD[k]] = ((unsigned)s << 8) | (unsigned)(d & 255);
        }
    }
}

// ---------------- per-bucket degree counts -> ns, nd, gcnt ----------------
__global__ __launch_bounds__(256) void k_degrees(const unsigned char* __restrict__ srecs,
        const unsigned* __restrict__ drecs, const int* __restrict__ tab,
        const int* __restrict__ seg, float* __restrict__ ns, float* __restrict__ nd,
        int* __restrict__ gcnt, int N, int NBK, int NBC, int E) {
    __shared__ int oc[256], ic[256];
    const int b = blockIdx.x, t = threadIdx.x;
    oc[t] = 0; ic[t] = 0;
    __syncthreads();
    const int sA0 = tab[(size_t)b * NBC];
    const int sA1 = tab[(size_t)(b + 1) * NBC];
    const int dA0 = tab[(size_t)(NBK + b) * NBC] - E;
    const int dA1 = tab[(size_t)(NBK + b + 1) * NBC] - E;
    for (int i = sA0 + t; i < sA1; i += 256) atomicAdd(&oc[srecs[i]], 1);
    for (int i = dA0 + t; i < dA1; i += 256) atomicAdd(&ic[drecs[i] & 255], 1);
    __syncthreads();
    const int node = (b << 8) + t;
    if (node < N) {
        ns[node] = rsqrtf(fmaxf((float)oc[t], 1.f));
        nd[node] = rsqrtf(fmaxf((float)ic[t], 1.f));
        atomicAdd(&gcnt[seg[node]], 1);
    }
}

// ---------------- projection: Hb[n][c] = bf16((X[n,:].W[:,c]) * ns[n]) ----------------
__global__ __launch_bounds__(256) void k_gemm(const float* __restrict__ X,
                                              const float* __restrict__ W,
                                              const float* __restrict__ ns,
                                              unsigned short* __restrict__ Hb, int N) {
    __shared__ __align__(16) float lx[256 * 36];
    __shared__ __align__(16) float lw[16 * 260];
    const int t = threadIdx.x;
    const int node0 = blockIdx.x * 256;

    for (int i = t; i < 256 * 16; i += 256) {
        int k = i >> 4, c = i & 15;
        lw[c * 260 + k] = W[i];
    }

    const int m  = t >> 2;
    const int cb = (t & 3) * 4;

    float4 acc[4][4];
#pragma unroll
    for (int j = 0; j < 4; ++j)
#pragma unroll
        for (int ci = 0; ci < 4; ++ci) acc[j][ci] = float4{0.f, 0.f, 0.f, 0.f};

    for (int kt = 0; kt < 8; ++kt) {
        const int k0 = kt * 32;
        __syncthreads();
#pragma unroll
        for (int i = 0; i < 8; ++i) {
            int f = t + 256 * i;
            int row = f >> 3, c4 = f & 7;
            float4 v = float4{0.f, 0.f, 0.f, 0.f};
            int node = node0 + row;
            if (node < N) v = *(const float4*)&X[(size_t)node * 256 + k0 + c4 * 4];
            *(float4*)&lx[row * 36 + c4 * 4] = v;
        }
        __syncthreads();
#pragma unroll
        for (int kk = 0; kk < 32; kk += 4) {
            float4 wv[4], xv[4];
#pragma unroll
            for (int ci = 0; ci < 4; ++ci)
                wv[ci] = *(const float4*)&lw[(cb + ci) * 260 + k0 + kk];
#pragma unroll
            for (int j = 0; j < 4; ++j)
                xv[j] = *(const float4*)&lx[(m + 64 * j) * 36 + kk];
#pragma unroll
            for (int j = 0; j < 4; ++j)
#pragma unroll
                for (int ci = 0; ci < 4; ++ci) {
                    acc[j][ci].x += xv[j].x * wv[ci].x;
                    acc[j][ci].y += xv[j].y * wv[ci].y;
                    acc[j][ci].z += xv[j].z * wv[ci].z;
                    acc[j][ci].w += xv[j].w * wv[ci].w;
                }
        }
    }

#pragma unroll
    for (int j = 0; j < 4; ++j) {
        int node = node0 + m + 64 * j;
        if (node < N) {
            float norm = ns[node];
            ushort4 o;
            float s0 = acc[j][0].x + acc[j][0].y + acc[j][0].z + acc[j][0].w;
            float s1 = acc[j][1].x + acc[j][1].y + acc[j][1].z + acc[j][1].w;
            float s2 = acc[j][2].x + acc[j][2].y + acc[j][2].z + acc[j][2].w;
            float s3 = acc[j][3].x + acc[j][3].y + acc[j][3].z + acc[j][3].w;
            o.x = f2bf(s0 * norm); o.y = f2bf(s1 * norm);
            o.z = f2bf(s2 * norm); o.w = f2bf(s3 * norm);
            *(ushort4*)&Hb[(size_t)node * 16 + cb] = o;
        }
    }
}

// ---------------- per-bucket edge accumulation in REGISTERS ----------------
__global__ __launch_bounds__(256) void k_gaccum(const unsigned* __restrict__ drecs,
        const int* __restrict__ tab, const int* __restrict__ seg,
        const float* __restrict__ nd, const unsigned short* __restrict__ Hb,
        float* __restrict__ outagg, int N, int NBK, int NBC, int E, int G) {
    __shared__ float lnd[256];
    __shared__ int   lgi[256];
    __shared__ float lhist[256];      // [16 slots][16 classes], rows 3..15 used
    __shared__ float wred[4 * 48];
    const int b = blockIdx.x >> 1, half = blockIdx.x & 1;
    const int t = threadIdx.x;
    const int node0 = b << 8;
    const int gf = seg[node0];
    lhist[t] = 0.f;
    const int node = node0 + t;
    if (node < N) {
        lnd[t] = nd[node];
        lgi[t] = seg[node] - gf;
    }
    __syncthreads();
    const int dA0 = tab[(size_t)(NBK + b) * NBC] - E;
    const int dA1 = tab[(size_t)(NBK + b + 1) * NBC] - E;
    const int mid = dA0 + ((dA1 - dA0) >> 1);
    const int i0 = half ? mid : dA0;
    const int i1 = half ? dA1 : mid;

    float a0[16], a1[16], a2[16];
#pragma unroll
    for (int j = 0; j < 16; ++j) { a0[j] = 0.f; a1[j] = 0.f; a2[j] = 0.f; }

    for (int i = i0 + t; i < i1; i += 256) {
        const unsigned r = drecs[i];
        const int dlow = r & 255;
        const int s = (int)(r >> 8);
        const float w = lnd[dlow];
        const int gi = lgi[dlow];
        const uint4* hp = (const uint4*)(Hb + (size_t)s * 16);
        const uint4 h0 = hp[0];
        const uint4 h1 = hp[1];
        if (gi < 3) {
            const float w0 = (gi == 0) ? w : 0.f;
            const float w1 = (gi == 1) ? w : 0.f;
            const float w2 = (gi == 2) ? w : 0.f;
#define ACC2(u, j0) { \
            float vlo = __uint_as_float((u) << 16); \
            float vhi = __uint_as_float((u) & 0xFFFF0000u); \
            a0[j0] += vlo * w0; a1[j0] += vlo * w1; a2[j0] += vlo * w2; \
            a0[j0+1] += vhi * w0; a1[j0+1] += vhi * w1; a2[j0+1] += vhi * w2; }
            ACC2(h0.x, 0) ACC2(h0.y, 2) ACC2(h0.z, 4) ACC2(h0.w, 6)
            ACC2(h1.x, 8) ACC2(h1.y, 10) ACC2(h1.z, 12) ACC2(h1.w, 14)
#undef ACC2
        } else {
            const unsigned hw[8] = {h0.x, h0.y, h0.z, h0.w, h1.x, h1.y, h1.z, h1.w};
            if (gi < 16) {
#pragma unroll
                for (int q = 0; q < 8; ++q) {
                    atomicAdd(&lhist[gi * 16 + 2 * q],     __uint_as_float(hw[q] << 16) * w);
                    atomicAdd(&lhist[gi * 16 + 2 * q + 1], __uint_as_float(hw[q] & 0xFFFF0000u) * w);
                }
            } else if (gf + gi < G) {   // astronomically rare
#pragma unroll
                for (int q = 0; q < 8; ++q) {
                    unsafeAtomicAdd(&outagg[(gf + gi) * 16 + 2 * q],     __uint_as_float(hw[q] << 16) * w);
                    unsafeAtomicAdd(&outagg[(gf + gi) * 16 + 2 * q + 1], __uint_as_float(hw[q] & 0xFFFF0000u) * w);
                }
            }
        }
    }

    // wave shuffle-reduce the 48 register sums
#pragma unroll
    for (int j = 0; j < 16; ++j) {
#pragma unroll
        for (int off = 32; off > 0; off >>= 1) {
            a0[j] += __shfl_down(a0[j], off, 64);
            a1[j] += __shfl_down(a1[j], off, 64);
            a2[j] += __shfl_down(a2[j], off, 64);
        }
    }
    const int wid = t >> 6, lane = t & 63;
    if (lane == 0) {
#pragma unroll
        for (int j = 0; j < 16; ++j) {
            wred[wid * 48 + j]      = a0[j];
            wred[wid * 48 + 16 + j] = a1[j];
            wred[wid * 48 + 32 + j] = a2[j];
        }
    }
    __syncthreads();
    if (t < 48) {
        const float v = wred[t] + wred[48 + t] + wred[96 + t] + wred[144 + t];
        const int g = gf + t / 16;
        if (v != 0.f && g < G) unsafeAtomicAdd(&outagg[g * 16 + (t & 15)], v);
    } else {
        const float v = lhist[t];       // rows 3..15 fallback
        const int g = gf + t / 16;
        if (v != 0.f && g < G) unsafeAtomicAdd(&outagg[g * 16 + (t & 15)], v);
    }
}

// ---------------- final: out = outagg / max(gcnt,1) + bias ----------------
__global__ void k_final(const float* __restrict__ outagg, const int* __restrict__ gcnt,
                        const float* __restrict__ bias, float* __restrict__ out, int G) {
    int i = blockIdx.x * 256 + threadIdx.x;
    if (i < G * 16)
        out[i] = outagg[i] / fmaxf((float)gcnt[i >> 4], 1.f) + bias[i & 15];
}

extern "C" void kernel_launch(void* const* d_in, const int* in_sizes, int n_in,
                              void* d_out, int out_size, void* d_ws, size_t ws_size,
                              hipStream_t stream) {
    const float* X  = (const float*)d_in[0];
    const float* W  = (const float*)d_in[1];
    const float* bb = (const float*)d_in[2];
    const int* esrc = (const int*)d_in[3];
    const int* edst = (const int*)d_in[4];
    const int* seg  = (const int*)d_in[5];
    const int N = in_sizes[5];                 // 100000
    const int E = in_sizes[3];                 // 3200000
    const int G = out_size / 16;               // 256
    const int NBK = (N + 255) >> 8;            // 391 (<=512 required)
    const int NBC = (E + KMAX * CTH - 1) / (KMAX * CTH);   // 500
    const int Ntab = 2 * NBK * NBC;            // 391000
    const int NBsc = (Ntab + 2047) / 2048;     // 191 scan blocks

    // ws layout (~18.4 MB; srecs/Hb aliased — srecs dead before gemm writes Hb)
    unsigned* drecs = (unsigned*)d_ws;                       // E u32 (12.8 MB)
    int* tab        = (int*)(drecs + (size_t)E);             // Ntab+1 ints
    int* bsum       = tab + (Ntab + 1);                      // NBsc (<=1024)
    float* ns       = (float*)(bsum + 1024);                 // N
    float* nd       = ns + N;                                // N
    float* outagg   = nd + N;                                // G*16  <- memset
    int* gcnt       = (int*)(outagg + (size_t)G * 16);       // G     <- memset
    unsigned char* srecs = (unsigned char*)(gcnt + G);       // E bytes \ aliased
    unsigned short* Hb   = (unsigned short*)srecs;           // N*16   / region

    hipMemsetAsync(outagg, 0, (size_t)G * 16 * 4 + (size_t)G * 4, stream);

    k_count  <<<NBC, CTH, 0, stream>>>(esrc, edst, tab, E, NBK, NBC);
    k_scanA  <<<NBsc, 256, 0, stream>>>(tab, bsum, Ntab);
    k_scanB  <<<1, 256, 0, stream>>>(bsum, NBsc);
    k_scanC  <<<NBsc, 256, 0, stream>>>(tab, bsum, Ntab);
    k_scatter<<<NBC, CTH, 0, stream>>>(esrc, edst, tab, srecs, drecs, E, NBK, NBC);
    k_degrees<<<NBK, 256, 0, stream>>>(srecs, drecs, tab, seg, ns, nd, gcnt, N, NBK, NBC, E);
    k_gemm   <<<(N + 255) / 256, 256, 0, stream>>>(X, W, ns, Hb, N);
    k_gaccum <<<NBK * 2, 256, 0, stream>>>(drecs, tab, seg, nd, Hb, outagg, N, NBK, NBC, E, G);
    k_final  <<<(G * 16 + 255) / 256, 256, 0, stream>>>(outagg, gcnt, bb, (float*)d_out, G);
}

// Round 7
// 370.529 us; speedup vs baseline: 3.0634x; 1.4070x over previous
//
#include <hip/hip_runtime.h>

#define KMAX 25            // unrolled edges per thread in count/scatter
#define CTH  256           // threads per count/scatter block

__device__ __forceinline__ unsigned short f2bf(float x) {   // RNE
    unsigned u = __float_as_uint(x);
    u += 0x7FFF + ((u >> 16) & 1);
    return (unsigned short)(u >> 16);
}

// ---------------- count events per (bucket, block) ----------------
__global__ __launch_bounds__(CTH) void k_count(const int* __restrict__ src,
        const int* __restrict__ dst, int* __restrict__ tab,
        int E, int NBK, int NBC) {
    __shared__ int cS[512], cD[512];
    const int t = threadIdx.x;
    for (int i = t; i < 512; i += CTH) { cS[i] = 0; cD[i] = 0; }
    __syncthreads();
    const int e0 = blockIdx.x * (KMAX * CTH);
    int e1 = e0 + KMAX * CTH; if (e1 > E) e1 = E;
    for (int e = e0 + t; e < e1; e += CTH) {
        atomicAdd(&cS[src[e] >> 8], 1);
        atomicAdd(&cD[dst[e] >> 8], 1);
    }
    __syncthreads();
    for (int b = t; b < NBK; b += CTH) {
        tab[(size_t)b * NBC + blockIdx.x]         = cS[b];
        tab[(size_t)(NBK + b) * NBC + blockIdx.x] = cD[b];
    }
}

// ---------------- hierarchical exclusive scan (3 phases) ----------------
__global__ __launch_bounds__(256) void k_scanA(const int* __restrict__ tab,
                                               int* __restrict__ bsum, int Ntab) {
    __shared__ int red[256];
    const int t = threadIdx.x;
    const int base = blockIdx.x * 2048 + t * 8;
    int s = 0;
#pragma unroll
    for (int k = 0; k < 8; ++k) { int i = base + k; if (i < Ntab) s += tab[i]; }
    red[t] = s; __syncthreads();
    for (int off = 128; off > 0; off >>= 1) {
        if (t < off) red[t] += red[t + off];
        __syncthreads();
    }
    if (t == 0) bsum[blockIdx.x] = red[0];
}

__global__ __launch_bounds__(256) void k_scanB(int* __restrict__ bsum, int NB) {
    __shared__ int sc[256];
    __shared__ int carry;
    const int t = threadIdx.x;
    if (t == 0) carry = 0;
    __syncthreads();
    for (int base = 0; base < NB; base += 256) {
        const int i = base + t;
        const int v = (i < NB) ? bsum[i] : 0;
        sc[t] = v; __syncthreads();
        for (int off = 1; off < 256; off <<= 1) {
            int add = (t >= off) ? sc[t - off] : 0;
            __syncthreads();
            sc[t] += add;
            __syncthreads();
        }
        if (i < NB) bsum[i] = carry + sc[t] - v;   // exclusive
        __syncthreads();
        if (t == 255) carry += sc[255];
        __syncthreads();
    }
}

__global__ __launch_bounds__(256) void k_scanC(int* __restrict__ tab,
                                               const int* __restrict__ bsum, int Ntab) {
    __shared__ int sc[256];
    const int t = threadIdx.x;
    const int base = blockIdx.x * 2048 + t * 8;
    int v[8]; int s = 0;
#pragma unroll
    for (int k = 0; k < 8; ++k) { int i = base + k; v[k] = (i < Ntab) ? tab[i] : 0; s += v[k]; }
    sc[t] = s; __syncthreads();
    for (int off = 1; off < 256; off <<= 1) {
        int add = (t >= off) ? sc[t - off] : 0;
        __syncthreads();
        sc[t] += add;
        __syncthreads();
    }
    int run = bsum[blockIdx.x] + sc[t] - s;
#pragma unroll
    for (int k = 0; k < 8; ++k) {
        int i = base + k;
        if (i < Ntab) { tab[i] = run; run += v[k]; }
    }
    if (base < Ntab && Ntab <= base + 8) tab[Ntab] = run;   // sentinel = 2E
}

// ---------------- scatter: src-events (1B) and dst-events (packed u32) ----------------
__global__ __launch_bounds__(CTH) void k_scatter(const int* __restrict__ src,
        const int* __restrict__ dst, const int* __restrict__ tab,
        unsigned char* __restrict__ srecs, unsigned* __restrict__ drecs,
        int E, int NBK, int NBC) {
    __shared__ int cS[512], cD[512];
    __shared__ int bS[512], bD[512];
    const int t = threadIdx.x;
    for (int i = t; i < 512; i += CTH) { cS[i] = 0; cD[i] = 0; }
    __syncthreads();
    const int e0 = blockIdx.x * (KMAX * CTH);
    int e1 = e0 + KMAX * CTH; if (e1 > E) e1 = E;
    unsigned short rS[KMAX], rD[KMAX];
#pragma unroll
    for (int k = 0; k < KMAX; ++k) {
        int e = e0 + k * CTH + t;
        if (e < e1) {
            rS[k] = (unsigned short)atomicAdd(&cS[src[e] >> 8], 1);
            rD[k] = (unsigned short)atomicAdd(&cD[dst[e] >> 8], 1);
        }
    }
    __syncthreads();
    for (int b = t; b < NBK; b += CTH) {
        bS[b] = tab[(size_t)b * NBC + blockIdx.x];
        bD[b] = tab[(size_t)(NBK + b) * NBC + blockIdx.x] - E;
    }
    __syncthreads();
#pragma unroll
    for (int k = 0; k < KMAX; ++k) {
        int e = e0 + k * CTH + t;
        if (e < e1) {
            int s = src[e], d = dst[e];
            srecs[bS[s >> 8] + rS[k]] = (unsigned char)(s & 255);
            drecs[bD[d >> 8] + rD[k]] = ((unsigned)s << 8) | (unsigned)(d & 255);
        }
    }
}

// ---------------- partial degree counts: 4 sub-blocks per bucket ----------------
// pdeg[(b*4+s)*256 + t] = outcount(u16) | incount(u16)<<16  (plain stores)
__global__ __launch_bounds__(256) void k_degA(const unsigned char* __restrict__ srecs,
        const unsigned* __restrict__ drecs, const int* __restrict__ tab,
        unsigned* __restrict__ pdeg, int NBK, int NBC, int E) {
    __shared__ int oc[256], ic[256];
    const int b = blockIdx.x >> 2, s = blockIdx.x & 3;
    const int t = threadIdx.x;
    oc[t] = 0; ic[t] = 0;
    __syncthreads();
    const int sA0 = tab[(size_t)b * NBC];
    const int sA1 = tab[(size_t)(b + 1) * NBC];
    const int dA0 = tab[(size_t)(NBK + b) * NBC] - E;
    const int dA1 = tab[(size_t)(NBK + b + 1) * NBC] - E;
    const int sl = sA1 - sA0, dl = dA1 - dA0;
    const int s0 = sA0 + (sl * s) / 4, s1 = sA0 + (sl * (s + 1)) / 4;
    const int d0 = dA0 + (dl * s) / 4, d1 = dA0 + (dl * (s + 1)) / 4;
    for (int i = s0 + t; i < s1; i += 256) atomicAdd(&oc[srecs[i]], 1);
    for (int i = d0 + t; i < d1; i += 256) atomicAdd(&ic[drecs[i] & 255], 1);
    __syncthreads();
    pdeg[(size_t)blockIdx.x * 256 + t] = (unsigned)oc[t] | ((unsigned)ic[t] << 16);
}

// ---------------- projection + degree fold ----------------
// grid = one block per 256-node bucket (same tiling as pdeg).
// Prologue: sum 4 pdeg partials -> ns (LDS-only) and nd (global, for gaccum).
__global__ __launch_bounds__(256) void k_gemm(const float* __restrict__ X,
                                              const float* __restrict__ W,
                                              const unsigned* __restrict__ pdeg,
                                              float* __restrict__ nd,
                                              unsigned short* __restrict__ Hb, int N) {
    __shared__ __align__(16) float lx[256 * 36];
    __shared__ __align__(16) float lw[16 * 260];
    __shared__ float lns[256];
    const int t = threadIdx.x;
    const int node0 = blockIdx.x * 256;

    {   // degree fold
        int od = 0, idg = 0;
#pragma unroll
        for (int s = 0; s < 4; ++s) {
            unsigned p = pdeg[(size_t)(blockIdx.x * 4 + s) * 256 + t];
            od  += (int)(p & 0xFFFFu);
            idg += (int)(p >> 16);
        }
        lns[t] = rsqrtf(fmaxf((float)od, 1.f));
        if (node0 + t < N) nd[node0 + t] = rsqrtf(fmaxf((float)idg, 1.f));
    }

    for (int i = t; i < 256 * 16; i += 256) {
        int k = i >> 4, c = i & 15;
        lw[c * 260 + k] = W[i];
    }

    const int m  = t >> 2;
    const int cb = (t & 3) * 4;

    float4 acc[4][4];
#pragma unroll
    for (int j = 0; j < 4; ++j)
#pragma unroll
        for (int ci = 0; ci < 4; ++ci) acc[j][ci] = float4{0.f, 0.f, 0.f, 0.f};

    for (int kt = 0; kt < 8; ++kt) {
        const int k0 = kt * 32;
        __syncthreads();
#pragma unroll
        for (int i = 0; i < 8; ++i) {
            int f = t + 256 * i;
            int row = f >> 3, c4 = f & 7;
            float4 v = float4{0.f, 0.f, 0.f, 0.f};
            int node = node0 + row;
            if (node < N) v = *(const float4*)&X[(size_t)node * 256 + k0 + c4 * 4];
            *(float4*)&lx[row * 36 + c4 * 4] = v;
        }
        __syncthreads();
#pragma unroll
        for (int kk = 0; kk < 32; kk += 4) {
            float4 wv[4], xv[4];
#pragma unroll
            for (int ci = 0; ci < 4; ++ci)
                wv[ci] = *(const float4*)&lw[(cb + ci) * 260 + k0 + kk];
#pragma unroll
            for (int j = 0; j < 4; ++j)
                xv[j] = *(const float4*)&lx[(m + 64 * j) * 36 + kk];
#pragma unroll
            for (int j = 0; j < 4; ++j)
#pragma unroll
                for (int ci = 0; ci < 4; ++ci) {
                    acc[j][ci].x += xv[j].x * wv[ci].x;
                    acc[j][ci].y += xv[j].y * wv[ci].y;
                    acc[j][ci].z += xv[j].z * wv[ci].z;
                    acc[j][ci].w += xv[j].w * wv[ci].w;
                }
        }
    }

#pragma unroll
    for (int j = 0; j < 4; ++j) {
        int node = node0 + m + 64 * j;
        if (node < N) {
            float norm = lns[m + 64 * j];
            ushort4 o;
            float s0 = acc[j][0].x + acc[j][0].y + acc[j][0].z + acc[j][0].w;
            float s1 = acc[j][1].x + acc[j][1].y + acc[j][1].z + acc[j][1].w;
            float s2 = acc[j][2].x + acc[j][2].y + acc[j][2].z + acc[j][2].w;
            float s3 = acc[j][3].x + acc[j][3].y + acc[j][3].z + acc[j][3].w;
            o.x = f2bf(s0 * norm); o.y = f2bf(s1 * norm);
            o.z = f2bf(s2 * norm); o.w = f2bf(s3 * norm);
            *(ushort4*)&Hb[(size_t)node * 16 + cb] = o;
        }
    }
}

// ---------------- per-bucket edge accumulation in REGISTERS ----------------
__global__ __launch_bounds__(256) void k_gaccum(const unsigned* __restrict__ drecs,
        const int* __restrict__ tab, const int* __restrict__ seg,
        const float* __restrict__ nd, const unsigned short* __restrict__ Hb,
        float* __restrict__ outagg, int N, int NBK, int NBC, int E, int G) {
    __shared__ float lnd[256];
    __shared__ int   lgi[256];
    __shared__ float lhist[256];      // [16 slots][16 classes], rows 3..15 used
    __shared__ float wred[4 * 48];
    const int b = blockIdx.x >> 1, half = blockIdx.x & 1;
    const int t = threadIdx.x;
    const int node0 = b << 8;
    const int gf = seg[node0];
    lhist[t] = 0.f;
    const int node = node0 + t;
    if (node < N) {
        lnd[t] = nd[node];
        lgi[t] = seg[node] - gf;
    }
    __syncthreads();
    const int dA0 = tab[(size_t)(NBK + b) * NBC] - E;
    const int dA1 = tab[(size_t)(NBK + b + 1) * NBC] - E;
    const int mid = dA0 + ((dA1 - dA0) >> 1);
    const int i0 = half ? mid : dA0;
    const int i1 = half ? dA1 : mid;

    float a0[16], a1[16], a2[16];
#pragma unroll
    for (int j = 0; j < 16; ++j) { a0[j] = 0.f; a1[j] = 0.f; a2[j] = 0.f; }

    for (int i = i0 + t; i < i1; i += 256) {
        const unsigned r = drecs[i];
        const int dlow = r & 255;
        const int s = (int)(r >> 8);
        const float w = lnd[dlow];
        const int gi = lgi[dlow];
        const uint4* hp = (const uint4*)(Hb + (size_t)s * 16);
        const uint4 h0 = hp[0];
        const uint4 h1 = hp[1];
        if (gi < 3) {
            const float w0 = (gi == 0) ? w : 0.f;
            const float w1 = (gi == 1) ? w : 0.f;
            const float w2 = (gi == 2) ? w : 0.f;
#define ACC2(u, j0) { \
            float vlo = __uint_as_float((u) << 16); \
            float vhi = __uint_as_float((u) & 0xFFFF0000u); \
            a0[j0] += vlo * w0; a1[j0] += vlo * w1; a2[j0] += vlo * w2; \
            a0[j0+1] += vhi * w0; a1[j0+1] += vhi * w1; a2[j0+1] += vhi * w2; }
            ACC2(h0.x, 0) ACC2(h0.y, 2) ACC2(h0.z, 4) ACC2(h0.w, 6)
            ACC2(h1.x, 8) ACC2(h1.y, 10) ACC2(h1.z, 12) ACC2(h1.w, 14)
#undef ACC2
        } else {
            const unsigned hw[8] = {h0.x, h0.y, h0.z, h0.w, h1.x, h1.y, h1.z, h1.w};
            if (gi < 16) {
#pragma unroll
                for (int q = 0; q < 8; ++q) {
                    atomicAdd(&lhist[gi * 16 + 2 * q],     __uint_as_float(hw[q] << 16) * w);
                    atomicAdd(&lhist[gi * 16 + 2 * q + 1], __uint_as_float(hw[q] & 0xFFFF0000u) * w);
                }
            } else if (gf + gi < G) {   // astronomically rare
#pragma unroll
                for (int q = 0; q < 8; ++q) {
                    unsafeAtomicAdd(&outagg[(gf + gi) * 16 + 2 * q],     __uint_as_float(hw[q] << 16) * w);
                    unsafeAtomicAdd(&outagg[(gf + gi) * 16 + 2 * q + 1], __uint_as_float(hw[q] & 0xFFFF0000u) * w);
                }
            }
        }
    }

#pragma unroll
    for (int j = 0; j < 16; ++j) {
#pragma unroll
        for (int off = 32; off > 0; off >>= 1) {
            a0[j] += __shfl_down(a0[j], off, 64);
            a1[j] += __shfl_down(a1[j], off, 64);
            a2[j] += __shfl_down(a2[j], off, 64);
        }
    }
    const int wid = t >> 6, lane = t & 63;
    if (lane == 0) {
#pragma unroll
        for (int j = 0; j < 16; ++j) {
            wred[wid * 48 + j]      = a0[j];
            wred[wid * 48 + 16 + j] = a1[j];
            wred[wid * 48 + 32 + j] = a2[j];
        }
    }
    __syncthreads();
    if (t < 48) {
        const float v = wred[t] + wred[48 + t] + wred[96 + t] + wred[144 + t];
        const int g = gf + t / 16;
        if (v != 0.f && g < G) unsafeAtomicAdd(&outagg[g * 16 + (t & 15)], v);
    } else {
        const float v = lhist[t];       // rows 3..15 fallback
        const int g = gf + t / 16;
        if (v != 0.f && g < G) unsafeAtomicAdd(&outagg[g * 16 + (t & 15)], v);
    }
}

// ---------------- final: gcnt via binary search (seg sorted) ----------------
__global__ void k_final(const float* __restrict__ outagg, const int* __restrict__ seg,
                        const float* __restrict__ bias, float* __restrict__ out,
                        int N, int G) {
    int i = blockIdx.x * 256 + threadIdx.x;
    if (i < G * 16) {
        const int g = i >> 4;
        int lo = 0, hi = N;
        while (lo < hi) { int md = (lo + hi) >> 1; if (seg[md] < g) lo = md + 1; else hi = md; }
        const int a = lo; hi = N;
        while (lo < hi) { int md = (lo + hi) >> 1; if (seg[md] <= g) lo = md + 1; else hi = md; }
        const float cnt = (float)(lo - a);
        out[i] = outagg[i] / fmaxf(cnt, 1.f) + bias[i & 15];
    }
}

extern "C" void kernel_launch(void* const* d_in, const int* in_sizes, int n_in,
                              void* d_out, int out_size, void* d_ws, size_t ws_size,
                              hipStream_t stream) {
    const float* X  = (const float*)d_in[0];
    const float* W  = (const float*)d_in[1];
    const float* bb = (const float*)d_in[2];
    const int* esrc = (const int*)d_in[3];
    const int* edst = (const int*)d_in[4];
    const int* seg  = (const int*)d_in[5];
    const int N = in_sizes[5];                 // 100000
    const int E = in_sizes[3];                 // 3200000
    const int G = out_size / 16;               // 256
    const int NBK = (N + 255) >> 8;            // 391 (<=512 required)
    const int NBC = (E + KMAX * CTH - 1) / (KMAX * CTH);   // 500
    const int Ntab = 2 * NBK * NBC;            // 391000
    const int NBsc = (Ntab + 2047) / 2048;     // 191 scan blocks

    // ws layout (~19.6 MB; srecs/Hb aliased — srecs dead after k_degA)
    unsigned* drecs = (unsigned*)d_ws;                       // E u32 (12.8 MB)
    int* tab        = (int*)(drecs + (size_t)E);             // Ntab+1 ints
    int* bsum       = tab + (Ntab + 1);                      // NBsc (<=1024)
    float* nd       = (float*)(bsum + 1024);                 // N
    float* outagg   = nd + N;                                // G*16  <- memset
    unsigned* pdeg  = (unsigned*)(outagg + (size_t)G * 16);  // NBK*4*256 (1.6 MB)
    unsigned char* srecs = (unsigned char*)(pdeg + (size_t)NBK * 4 * 256); // E bytes \ alias
    unsigned short* Hb   = (unsigned short*)srecs;                          // N*16   / region

    hipMemsetAsync(outagg, 0, (size_t)G * 16 * 4, stream);

    k_count  <<<NBC, CTH, 0, stream>>>(esrc, edst, tab, E, NBK, NBC);
    k_scanA  <<<NBsc, 256, 0, stream>>>(tab, bsum, Ntab);
    k_scanB  <<<1, 256, 0, stream>>>(bsum, NBsc);
    k_scanC  <<<NBsc, 256, 0, stream>>>(tab, bsum, Ntab);
    k_scatter<<<NBC, CTH, 0, stream>>>(esrc, edst, tab, srecs, drecs, E, NBK, NBC);
    k_degA   <<<NBK * 4, 256, 0, stream>>>(srecs, drecs, tab, pdeg, NBK, NBC, E);
    k_gemm   <<<NBK, 256, 0, stream>>>(X, W, pdeg, nd, Hb, N);
    k_gaccum <<<NBK * 2, 256, 0, stream>>>(drecs, tab, seg, nd, Hb, outagg, N, NBK, NBC, E, G);
    k_final  <<<(G * 16 + 255) / 256, 256, 0, stream>>>(outagg, seg, bb, (float*)d_out, N, G);
}

// Round 8
// 333.882 us; speedup vs baseline: 3.3996x; 1.1098x over previous
//
#include <hip/hip_runtime.h>

#define KMAX 17            // edges per thread in count/scatter
#define CTH  256           // threads per count/scatter block
#define EVB  (KMAX * CTH)  // 4352 events per block

__device__ __forceinline__ unsigned short f2bf(float x) {   // RNE
    unsigned u = __float_as_uint(x);
    u += 0x7FFF + ((u >> 16) & 1);
    return (unsigned short)(u >> 16);
}

// ---------------- count events per (bucket, block) ----------------
// col swizzle: same-XCD blocks (blk%8 equal) own adjacent tab columns.
__global__ __launch_bounds__(CTH) void k_count(const int* __restrict__ src,
        const int* __restrict__ dst, int* __restrict__ tab,
        int E, int NBK, int NBC) {
    __shared__ int cS[512], cD[512];
    const int t = threadIdx.x;
    for (int i = t; i < 512; i += CTH) { cS[i] = 0; cD[i] = 0; }
    __syncthreads();
    const int e0 = blockIdx.x * EVB;
    int e1 = e0 + EVB; if (e1 > E) e1 = E;
    for (int e = e0 + t; e < e1; e += CTH) {
        atomicAdd(&cS[src[e] >> 8], 1);
        atomicAdd(&cD[dst[e] >> 8], 1);
    }
    __syncthreads();
    const int col = (blockIdx.x & 7) * (NBC >> 3) + (blockIdx.x >> 3);
    for (int b = t; b < NBK; b += CTH) {
        tab[(size_t)b * NBC + col]         = cS[b];
        tab[(size_t)(NBK + b) * NBC + col] = cD[b];
    }
}

// ---------------- hierarchical exclusive scan (3 phases) ----------------
__global__ __launch_bounds__(256) void k_scanA(const int* __restrict__ tab,
                                               int* __restrict__ bsum, int Ntab) {
    __shared__ int red[256];
    const int t = threadIdx.x;
    const int base = blockIdx.x * 2048 + t * 8;
    int s = 0;
#pragma unroll
    for (int k = 0; k < 8; ++k) { int i = base + k; if (i < Ntab) s += tab[i]; }
    red[t] = s; __syncthreads();
    for (int off = 128; off > 0; off >>= 1) {
        if (t < off) red[t] += red[t + off];
        __syncthreads();
    }
    if (t == 0) bsum[blockIdx.x] = red[0];
}

__global__ __launch_bounds__(256) void k_scanB(int* __restrict__ bsum, int NB) {
    __shared__ int sc[256];
    __shared__ int carry;
    const int t = threadIdx.x;
    if (t == 0) carry = 0;
    __syncthreads();
    for (int base = 0; base < NB; base += 256) {
        const int i = base + t;
        const int v = (i < NB) ? bsum[i] : 0;
        sc[t] = v; __syncthreads();
        for (int off = 1; off < 256; off <<= 1) {
            int add = (t >= off) ? sc[t - off] : 0;
            __syncthreads();
            sc[t] += add;
            __syncthreads();
        }
        if (i < NB) bsum[i] = carry + sc[t] - v;   // exclusive
        __syncthreads();
        if (t == 255) carry += sc[255];
        __syncthreads();
    }
}

__global__ __launch_bounds__(256) void k_scanC(int* __restrict__ tab,
                                               const int* __restrict__ bsum, int Ntab) {
    __shared__ int sc[256];
    const int t = threadIdx.x;
    const int base = blockIdx.x * 2048 + t * 8;
    int v[8]; int s = 0;
#pragma unroll
    for (int k = 0; k < 8; ++k) { int i = base + k; v[k] = (i < Ntab) ? tab[i] : 0; s += v[k]; }
    sc[t] = s; __syncthreads();
    for (int off = 1; off < 256; off <<= 1) {
        int add = (t >= off) ? sc[t - off] : 0;
        __syncthreads();
        sc[t] += add;
        __syncthreads();
    }
    int run = bsum[blockIdx.x] + sc[t] - s;
#pragma unroll
    for (int k = 0; k < 8; ++k) {
        int i = base + k;
        if (i < Ntab) { tab[i] = run; run += v[k]; }
    }
    if (base < Ntab && Ntab <= base + 8) tab[Ntab] = run;   // sentinel = 2E
}

// ---------------- scatter: LDS-staged, bucket-ordered dump ----------------
// Rank into LDS staging ordered by bucket (packed u32 counters: lo16=src,
// hi16=dst), then dump linearly: consecutive lanes -> consecutive addresses.
__global__ __launch_bounds__(CTH) void k_scatter(const int* __restrict__ src,
        const int* __restrict__ dst, const int* __restrict__ tab,
        unsigned char* __restrict__ srecs, unsigned* __restrict__ drecs,
        int E, int NBK, int NBC) {
    __shared__ unsigned dstage[EVB];          // 17.4 KB
    __shared__ unsigned char sstage[EVB];     // 4.4 KB
    __shared__ unsigned off[513];             // packed exclusive offsets
    __shared__ unsigned pos[512];             // packed running counters
    __shared__ int bS[512], bD[512];
    __shared__ unsigned red[256];
    const int t = threadIdx.x;
    pos[t] = 0; pos[t + 256] = 0;
    __syncthreads();
    const int e0 = blockIdx.x * EVB;
    const int e1full = e0 + EVB;
    const int e1 = (e1full > E) ? E : e1full;

    int sv[KMAX], dv[KMAX];
#pragma unroll
    for (int k = 0; k < KMAX; ++k) {
        const int e = e0 + k * CTH + t;
        if (e < e1) {
            sv[k] = src[e]; dv[k] = dst[e];
            atomicAdd(&pos[sv[k] >> 8], 1u);
            atomicAdd(&pos[dv[k] >> 8], 0x10000u);
        }
    }
    __syncthreads();
    // exclusive scan of pos[0..511] (2 entries/thread; packed halves independent)
    const unsigned v0 = pos[2 * t], v1 = pos[2 * t + 1];
    const unsigned ps = v0 + v1;
    red[t] = ps;
    __syncthreads();
    for (int o = 1; o < 256; o <<= 1) {
        unsigned add = (t >= o) ? red[t - o] : 0;
        __syncthreads();
        red[t] += add;
        __syncthreads();
    }
    const unsigned base = red[t] - ps;
    off[2 * t] = base;
    off[2 * t + 1] = base + v0;
    if (t == 255) off[512] = red[255];
    __syncthreads();
    pos[t] = off[t]; pos[t + 256] = off[t + 256];
    __syncthreads();
    // rank + LDS scatter
#pragma unroll
    for (int k = 0; k < KMAX; ++k) {
        const int e = e0 + k * CTH + t;
        if (e < e1) {
            const int s = sv[k], d = dv[k];
            const unsigned rs = atomicAdd(&pos[s >> 8], 1u);
            sstage[rs & 0xFFFFu] = (unsigned char)(s & 255);
            const unsigned rd = atomicAdd(&pos[d >> 8], 0x10000u);
            dstage[rd >> 16] = ((unsigned)s << 8) | (unsigned)(d & 255);
        }
    }
    const int col = (blockIdx.x & 7) * (NBC >> 3) + (blockIdx.x >> 3);
    for (int b = t; b < NBK; b += CTH) {
        bS[b] = tab[(size_t)b * NBC + col];
        bD[b] = tab[(size_t)(NBK + b) * NBC + col] - E;
    }
    __syncthreads();
    const int tot = e1 - e0;
    for (int slot = t; slot < tot; slot += CTH) {       // srecs dump
        int lo = 0, hi = NBK;
        while (hi - lo > 1) {
            const int md = (lo + hi) >> 1;
            if ((off[md] & 0xFFFFu) <= (unsigned)slot) lo = md; else hi = md;
        }
        srecs[bS[lo] + slot - (int)(off[lo] & 0xFFFFu)] = sstage[slot];
    }
    for (int slot = t; slot < tot; slot += CTH) {       // drecs dump
        int lo = 0, hi = NBK;
        while (hi - lo > 1) {
            const int md = (lo + hi) >> 1;
            if ((off[md] >> 16) <= (unsigned)slot) lo = md; else hi = md;
        }
        drecs[bD[lo] + slot - (int)(off[lo] >> 16)] = dstage[slot];
    }
}

// ---------------- partial degree counts: 4 sub-blocks per bucket ----------------
__global__ __launch_bounds__(256) void k_degA(const unsigned char* __restrict__ srecs,
        const unsigned* __restrict__ drecs, const int* __restrict__ tab,
        unsigned* __restrict__ pdeg, int NBK, int NBC, int E) {
    __shared__ int oc[256], ic[256];
    const int b = blockIdx.x >> 2, s = blockIdx.x & 3;
    const int t = threadIdx.x;
    oc[t] = 0; ic[t] = 0;
    __syncthreads();
    const int sA0 = tab[(size_t)b * NBC];
    const int sA1 = tab[(size_t)(b + 1) * NBC];
    const int dA0 = tab[(size_t)(NBK + b) * NBC] - E;
    const int dA1 = tab[(size_t)(NBK + b + 1) * NBC] - E;
    const int sl = sA1 - sA0, dl = dA1 - dA0;
    const int s0 = sA0 + (sl * s) / 4, s1 = sA0 + (sl * (s + 1)) / 4;
    const int d0 = dA0 + (dl * s) / 4, d1 = dA0 + (dl * (s + 1)) / 4;
    for (int i = s0 + t; i < s1; i += 256) atomicAdd(&oc[srecs[i]], 1);
    for (int i = d0 + t; i < d1; i += 256) atomicAdd(&ic[drecs[i] & 255], 1);
    __syncthreads();
    pdeg[(size_t)blockIdx.x * 256 + t] = (unsigned)oc[t] | ((unsigned)ic[t] << 16);
}

// ---------------- projection + degree fold (128-node tiles) ----------------
__global__ __launch_bounds__(256) void k_gemm(const float* __restrict__ X,
                                              const float* __restrict__ W,
                                              const unsigned* __restrict__ pdeg,
                                              float* __restrict__ nd,
                                              unsigned short* __restrict__ Hb, int N) {
    __shared__ __align__(16) float lx[128 * 36];   // 18.4 KB
    __shared__ __align__(16) float lw[16 * 260];   // 16.6 KB
    __shared__ float lns[128];
    const int t = threadIdx.x;
    const int node0 = blockIdx.x * 128;

    if (t < 128) {   // degree fold (pdeg tiled per 256-node bucket)
        const int node = node0 + t;
        const int bk = node >> 8, w = node & 255;
        int od = 0, idg = 0;
#pragma unroll
        for (int s = 0; s < 4; ++s) {
            const unsigned p = pdeg[(size_t)(bk * 4 + s) * 256 + w];
            od  += (int)(p & 0xFFFFu);
            idg += (int)(p >> 16);
        }
        lns[t] = rsqrtf(fmaxf((float)od, 1.f));
        if (node < N) nd[node] = rsqrtf(fmaxf((float)idg, 1.f));
    }

    for (int i = t; i < 256 * 16; i += 256) {
        const int k = i >> 4, c = i & 15;
        lw[c * 260 + k] = W[i];
    }

    const int m  = t >> 2;         // 0..63
    const int cb = (t & 3) * 4;

    float4 acc[2][4];
#pragma unroll
    for (int j = 0; j < 2; ++j)
#pragma unroll
        for (int ci = 0; ci < 4; ++ci) acc[j][ci] = float4{0.f, 0.f, 0.f, 0.f};

    for (int kt = 0; kt < 8; ++kt) {
        const int k0 = kt * 32;
        __syncthreads();
#pragma unroll
        for (int i = 0; i < 4; ++i) {
            const int f = t + 256 * i;          // 0..1023
            const int row = f >> 3, c4 = f & 7;
            float4 v = float4{0.f, 0.f, 0.f, 0.f};
            const int node = node0 + row;
            if (node < N) v = *(const float4*)&X[(size_t)node * 256 + k0 + c4 * 4];
            *(float4*)&lx[row * 36 + c4 * 4] = v;
        }
        __syncthreads();
#pragma unroll
        for (int kk = 0; kk < 32; kk += 4) {
            float4 wv[4], xv[2];
#pragma unroll
            for (int ci = 0; ci < 4; ++ci)
                wv[ci] = *(const float4*)&lw[(cb + ci) * 260 + k0 + kk];
#pragma unroll
            for (int j = 0; j < 2; ++j)
                xv[j] = *(const float4*)&lx[(m + 64 * j) * 36 + kk];
#pragma unroll
            for (int j = 0; j < 2; ++j)
#pragma unroll
                for (int ci = 0; ci < 4; ++ci) {
                    acc[j][ci].x += xv[j].x * wv[ci].x;
                    acc[j][ci].y += xv[j].y * wv[ci].y;
                    acc[j][ci].z += xv[j].z * wv[ci].z;
                    acc[j][ci].w += xv[j].w * wv[ci].w;
                }
        }
    }

#pragma unroll
    for (int j = 0; j < 2; ++j) {
        const int node = node0 + m + 64 * j;
        if (node < N) {
            const float norm = lns[m + 64 * j];
            ushort4 o;
            const float s0 = acc[j][0].x + acc[j][0].y + acc[j][0].z + acc[j][0].w;
            const float s1 = acc[j][1].x + acc[j][1].y + acc[j][1].z + acc[j][1].w;
            const float s2 = acc[j][2].x + acc[j][2].y + acc[j][2].z + acc[j][2].w;
            const float s3 = acc[j][3].x + acc[j][3].y + acc[j][3].z + acc[j][3].w;
            o.x = f2bf(s0 * norm); o.y = f2bf(s1 * norm);
            o.z = f2bf(s2 * norm); o.w = f2bf(s3 * norm);
            *(ushort4*)&Hb[(size_t)node * 16 + cb] = o;
        }
    }
}

// ---------------- per-bucket edge accumulation in REGISTERS ----------------
__global__ __launch_bounds__(256) void k_gaccum(const unsigned* __restrict__ drecs,
        const int* __restrict__ tab, const int* __restrict__ seg,
        const float* __restrict__ nd, const unsigned short* __restrict__ Hb,
        float* __restrict__ outagg, int N, int NBK, int NBC, int E, int G) {
    __shared__ float lnd[256];
    __shared__ int   lgi[256];
    __shared__ float lhist[256];
    __shared__ float wred[4 * 48];
    const int b = blockIdx.x >> 1, half = blockIdx.x & 1;
    const int t = threadIdx.x;
    const int node0 = b << 8;
    const int gf = seg[node0];
    lhist[t] = 0.f;
    const int node = node0 + t;
    if (node < N) {
        lnd[t] = nd[node];
        lgi[t] = seg[node] - gf;
    }
    __syncthreads();
    const int dA0 = tab[(size_t)(NBK + b) * NBC] - E;
    const int dA1 = tab[(size_t)(NBK + b + 1) * NBC] - E;
    const int mid = dA0 + ((dA1 - dA0) >> 1);
    const int i0 = half ? mid : dA0;
    const int i1 = half ? dA1 : mid;

    float a0[16], a1[16], a2[16];
#pragma unroll
    for (int j = 0; j < 16; ++j) { a0[j] = 0.f; a1[j] = 0.f; a2[j] = 0.f; }

    for (int i = i0 + t; i < i1; i += 256) {
        const unsigned r = drecs[i];
        const int dlow = r & 255;
        const int s = (int)(r >> 8);
        const float w = lnd[dlow];
        const int gi = lgi[dlow];
        const uint4* hp = (const uint4*)(Hb + (size_t)s * 16);
        const uint4 h0 = hp[0];
        const uint4 h1 = hp[1];
        if (gi < 3) {
            const float w0 = (gi == 0) ? w : 0.f;
            const float w1 = (gi == 1) ? w : 0.f;
            const float w2 = (gi == 2) ? w : 0.f;
#define ACC2(u, j0) { \
            float vlo = __uint_as_float((u) << 16); \
            float vhi = __uint_as_float((u) & 0xFFFF0000u); \
            a0[j0] += vlo * w0; a1[j0] += vlo * w1; a2[j0] += vlo * w2; \
            a0[j0+1] += vhi * w0; a1[j0+1] += vhi * w1; a2[j0+1] += vhi * w2; }
            ACC2(h0.x, 0) ACC2(h0.y, 2) ACC2(h0.z, 4) ACC2(h0.w, 6)
            ACC2(h1.x, 8) ACC2(h1.y, 10) ACC2(h1.z, 12) ACC2(h1.w, 14)
#undef ACC2
        } else {
            const unsigned hw[8] = {h0.x, h0.y, h0.z, h0.w, h1.x, h1.y, h1.z, h1.w};
            if (gi < 16) {
#pragma unroll
                for (int q = 0; q < 8; ++q) {
                    atomicAdd(&lhist[gi * 16 + 2 * q],     __uint_as_float(hw[q] << 16) * w);
                    atomicAdd(&lhist[gi * 16 + 2 * q + 1], __uint_as_float(hw[q] & 0xFFFF0000u) * w);
                }
            } else if (gf + gi < G) {
#pragma unroll
                for (int q = 0; q < 8; ++q) {
                    unsafeAtomicAdd(&outagg[(gf + gi) * 16 + 2 * q],     __uint_as_float(hw[q] << 16) * w);
                    unsafeAtomicAdd(&outagg[(gf + gi) * 16 + 2 * q + 1], __uint_as_float(hw[q] & 0xFFFF0000u) * w);
                }
            }
        }
    }

#pragma unroll
    for (int j = 0; j < 16; ++j) {
#pragma unroll
        for (int off = 32; off > 0; off >>= 1) {
            a0[j] += __shfl_down(a0[j], off, 64);
            a1[j] += __shfl_down(a1[j], off, 64);
            a2[j] += __shfl_down(a2[j], off, 64);
        }
    }
    const int wid = t >> 6, lane = t & 63;
    if (lane == 0) {
#pragma unroll
        for (int j = 0; j < 16; ++j) {
            wred[wid * 48 + j]      = a0[j];
            wred[wid * 48 + 16 + j] = a1[j];
            wred[wid * 48 + 32 + j] = a2[j];
        }
    }
    __syncthreads();
    if (t < 48) {
        const float v = wred[t] + wred[48 + t] + wred[96 + t] + wred[144 + t];
        const int g = gf + t / 16;
        if (v != 0.f && g < G) unsafeAtomicAdd(&outagg[g * 16 + (t & 15)], v);
    } else {
        const float v = lhist[t];
        const int g = gf + t / 16;
        if (v != 0.f && g < G) unsafeAtomicAdd(&outagg[g * 16 + (t & 15)], v);
    }
}

// ---------------- final: gcnt via binary search (seg sorted) ----------------
__global__ void k_final(const float* __restrict__ outagg, const int* __restrict__ seg,
                        const float* __restrict__ bias, float* __restrict__ out,
                        int N, int G) {
    int i = blockIdx.x * 256 + threadIdx.x;
    if (i < G * 16) {
        const int g = i >> 4;
        int lo = 0, hi = N;
        while (lo < hi) { int md = (lo + hi) >> 1; if (seg[md] < g) lo = md + 1; else hi = md; }
        const int a = lo; hi = N;
        while (lo < hi) { int md = (lo + hi) >> 1; if (seg[md] <= g) lo = md + 1; else hi = md; }
        const float cnt = (float)(lo - a);
        out[i] = outagg[i] / fmaxf(cnt, 1.f) + bias[i & 15];
    }
}

extern "C" void kernel_launch(void* const* d_in, const int* in_sizes, int n_in,
                              void* d_out, int out_size, void* d_ws, size_t ws_size,
                              hipStream_t stream) {
    const float* X  = (const float*)d_in[0];
    const float* W  = (const float*)d_in[1];
    const float* bb = (const float*)d_in[2];
    const int* esrc = (const int*)d_in[3];
    const int* edst = (const int*)d_in[4];
    const int* seg  = (const int*)d_in[5];
    const int N = in_sizes[5];                 // 100000
    const int E = in_sizes[3];                 // 3200000
    const int G = out_size / 16;               // 256
    const int NBK = (N + 255) >> 8;            // 391 (<=512 required)
    const int NBC = (((E + EVB - 1) / EVB) + 7) & ~7;   // 736 (x8 for swizzle)
    const int Ntab = 2 * NBK * NBC;            // 575552
    const int NBsc = (Ntab + 2047) / 2048;     // 282 scan blocks

    // ws layout (~20.3 MB; srecs/Hb aliased — srecs dead after k_degA)
    unsigned* drecs = (unsigned*)d_ws;                       // E u32 (12.8 MB)
    int* tab        = (int*)(drecs + (size_t)E);             // Ntab+1 ints (2.3 MB)
    int* bsum       = tab + (Ntab + 1);                      // NBsc (<=1024)
    float* nd       = (float*)(bsum + 1024);                 // N
    float* outagg   = nd + N;                                // G*16  <- memset
    unsigned* pdeg  = (unsigned*)(outagg + (size_t)G * 16);  // NBK*4*256 (1.6 MB)
    unsigned char* srecs = (unsigned char*)(pdeg + (size_t)NBK * 4 * 256); // E bytes \ alias
    unsigned short* Hb   = (unsigned short*)srecs;                          // N*16   / region

    hipMemsetAsync(outagg, 0, (size_t)G * 16 * 4, stream);

    k_count  <<<NBC, CTH, 0, stream>>>(esrc, edst, tab, E, NBK, NBC);
    k_scanA  <<<NBsc, 256, 0, stream>>>(tab, bsum, Ntab);
    k_scanB  <<<1, 256, 0, stream>>>(bsum, NBsc);
    k_scanC  <<<NBsc, 256, 0, stream>>>(tab, bsum, Ntab);
    k_scatter<<<NBC, CTH, 0, stream>>>(esrc, edst, tab, srecs, drecs, E, NBK, NBC);
    k_degA   <<<NBK * 4, 256, 0, stream>>>(srecs, drecs, tab, pdeg, NBK, NBC, E);
    k_gemm   <<<(N + 127) / 128, 256, 0, stream>>>(X, W, pdeg, nd, Hb, N);
    k_gaccum <<<NBK * 2, 256, 0, stream>>>(drecs, tab, seg, nd, Hb, outagg, N, NBK, NBC, E, G);
    k_final  <<<(G * 16 + 255) / 256, 256, 0, stream>>>(outagg, seg, bb, (float*)d_out, N, G);
}

// Round 9
// 325.281 us; speedup vs baseline: 3.4895x; 1.0264x over previous
//
#include <hip/hip_runtime.h>

#define KMAX 17            // edges per thread in count/scatter
#define CTH  256           // threads per count/scatter block
#define EVB  (KMAX * CTH)  // 4352 events per block

__device__ __forceinline__ unsigned short f2bf(float x) {   // RNE
    unsigned u = __float_as_uint(x);
    u += 0x7FFF + ((u >> 16) & 1);
    return (unsigned short)(u >> 16);
}

// ---------------- count events per (bucket, block) ----------------
__global__ __launch_bounds__(CTH) void k_count(const int* __restrict__ src,
        const int* __restrict__ dst, int* __restrict__ tab,
        int E, int NBK, int NBC) {
    __shared__ int cS[512], cD[512];
    const int t = threadIdx.x;
    for (int i = t; i < 512; i += CTH) { cS[i] = 0; cD[i] = 0; }
    __syncthreads();
    const int e0 = blockIdx.x * EVB;
    int e1 = e0 + EVB; if (e1 > E) e1 = E;
    for (int e = e0 + t; e < e1; e += CTH) {
        atomicAdd(&cS[src[e] >> 8], 1);
        atomicAdd(&cD[dst[e] >> 8], 1);
    }
    __syncthreads();
    const int col = (blockIdx.x & 7) * (NBC >> 3) + (blockIdx.x >> 3);
    for (int b = t; b < NBK; b += CTH) {
        tab[(size_t)b * NBC + col]         = cS[b];
        tab[(size_t)(NBK + b) * NBC + col] = cD[b];
    }
}

// ---------------- hierarchical exclusive scan (3 phases) ----------------
__global__ __launch_bounds__(256) void k_scanA(const int* __restrict__ tab,
                                               int* __restrict__ bsum, int Ntab) {
    __shared__ int red[256];
    const int t = threadIdx.x;
    const int base = blockIdx.x * 2048 + t * 8;
    int s = 0;
#pragma unroll
    for (int k = 0; k < 8; ++k) { int i = base + k; if (i < Ntab) s += tab[i]; }
    red[t] = s; __syncthreads();
    for (int off = 128; off > 0; off >>= 1) {
        if (t < off) red[t] += red[t + off];
        __syncthreads();
    }
    if (t == 0) bsum[blockIdx.x] = red[0];
}

__global__ __launch_bounds__(256) void k_scanB(int* __restrict__ bsum, int NB) {
    __shared__ int sc[256];
    __shared__ int carry;
    const int t = threadIdx.x;
    if (t == 0) carry = 0;
    __syncthreads();
    for (int base = 0; base < NB; base += 256) {
        const int i = base + t;
        const int v = (i < NB) ? bsum[i] : 0;
        sc[t] = v; __syncthreads();
        for (int off = 1; off < 256; off <<= 1) {
            int add = (t >= off) ? sc[t - off] : 0;
            __syncthreads();
            sc[t] += add;
            __syncthreads();
        }
        if (i < NB) bsum[i] = carry + sc[t] - v;   // exclusive
        __syncthreads();
        if (t == 255) carry += sc[255];
        __syncthreads();
    }
}

__global__ __launch_bounds__(256) void k_scanC(int* __restrict__ tab,
                                               const int* __restrict__ bsum, int Ntab) {
    __shared__ int sc[256];
    const int t = threadIdx.x;
    const int base = blockIdx.x * 2048 + t * 8;
    int v[8]; int s = 0;
#pragma unroll
    for (int k = 0; k < 8; ++k) { int i = base + k; v[k] = (i < Ntab) ? tab[i] : 0; s += v[k]; }
    sc[t] = s; __syncthreads();
    for (int off = 1; off < 256; off <<= 1) {
        int add = (t >= off) ? sc[t - off] : 0;
        __syncthreads();
        sc[t] += add;
        __syncthreads();
    }
    int run = bsum[blockIdx.x] + sc[t] - s;
#pragma unroll
    for (int k = 0; k < 8; ++k) {
        int i = base + k;
        if (i < Ntab) { tab[i] = run; run += v[k]; }
    }
    if (base < Ntab && Ntab <= base + 8) tab[Ntab] = run;   // sentinel = 2E
}

// ---------------- scatter: LDS-staged, bucket-ordered dump ----------------
__global__ __launch_bounds__(CTH) void k_scatter(const int* __restrict__ src,
        const int* __restrict__ dst, const int* __restrict__ tab,
        unsigned char* __restrict__ srecs, unsigned* __restrict__ drecs,
        int E, int NBK, int NBC) {
    __shared__ unsigned dstage[EVB];          // 17.4 KB
    __shared__ unsigned char sstage[EVB];     // 4.4 KB
    __shared__ unsigned off[513];             // packed exclusive offsets
    __shared__ unsigned pos[512];             // packed running counters
    __shared__ int bS[512], bD[512];
    __shared__ unsigned red[256];
    const int t = threadIdx.x;
    pos[t] = 0; pos[t + 256] = 0;
    __syncthreads();
    const int e0 = blockIdx.x * EVB;
    const int e1full = e0 + EVB;
    const int e1 = (e1full > E) ? E : e1full;

    int sv[KMAX], dv[KMAX];
#pragma unroll
    for (int k = 0; k < KMAX; ++k) {
        const int e = e0 + k * CTH + t;
        if (e < e1) {
            sv[k] = src[e]; dv[k] = dst[e];
            atomicAdd(&pos[sv[k] >> 8], 1u);
            atomicAdd(&pos[dv[k] >> 8], 0x10000u);
        }
    }
    __syncthreads();
    const unsigned v0 = pos[2 * t], v1 = pos[2 * t + 1];
    const unsigned ps = v0 + v1;
    red[t] = ps;
    __syncthreads();
    for (int o = 1; o < 256; o <<= 1) {
        unsigned add = (t >= o) ? red[t - o] : 0;
        __syncthreads();
        red[t] += add;
        __syncthreads();
    }
    const unsigned base = red[t] - ps;
    off[2 * t] = base;
    off[2 * t + 1] = base + v0;
    if (t == 255) off[512] = red[255];
    __syncthreads();
    pos[t] = off[t]; pos[t + 256] = off[t + 256];
    __syncthreads();
#pragma unroll
    for (int k = 0; k < KMAX; ++k) {
        const int e = e0 + k * CTH + t;
        if (e < e1) {
            const int s = sv[k], d = dv[k];
            const unsigned rs = atomicAdd(&pos[s >> 8], 1u);
            sstage[rs & 0xFFFFu] = (unsigned char)(s & 255);
            const unsigned rd = atomicAdd(&pos[d >> 8], 0x10000u);
            dstage[rd >> 16] = ((unsigned)s << 8) | (unsigned)(d & 255);
        }
    }
    const int col = (blockIdx.x & 7) * (NBC >> 3) + (blockIdx.x >> 3);
    for (int b = t; b < NBK; b += CTH) {
        bS[b] = tab[(size_t)b * NBC + col];
        bD[b] = tab[(size_t)(NBK + b) * NBC + col] - E;
    }
    __syncthreads();
    const int tot = e1 - e0;
    for (int slot = t; slot < tot; slot += CTH) {       // srecs dump
        int lo = 0, hi = NBK;
        while (hi - lo > 1) {
            const int md = (lo + hi) >> 1;
            if ((off[md] & 0xFFFFu) <= (unsigned)slot) lo = md; else hi = md;
        }
        srecs[bS[lo] + slot - (int)(off[lo] & 0xFFFFu)] = sstage[slot];
    }
    for (int slot = t; slot < tot; slot += CTH) {       // drecs dump
        int lo = 0, hi = NBK;
        while (hi - lo > 1) {
            const int md = (lo + hi) >> 1;
            if ((off[md] >> 16) <= (unsigned)slot) lo = md; else hi = md;
        }
        drecs[bD[lo] + slot - (int)(off[lo] >> 16)] = dstage[slot];
    }
}

// ---------------- partial degree counts: 4 sub-blocks per bucket ----------------
__global__ __launch_bounds__(256) void k_degA(const unsigned char* __restrict__ srecs,
        const unsigned* __restrict__ drecs, const int* __restrict__ tab,
        unsigned* __restrict__ pdeg, int NBK, int NBC, int E) {
    __shared__ int oc[256], ic[256];
    const int b = blockIdx.x >> 2, s = blockIdx.x & 3;
    const int t = threadIdx.x;
    oc[t] = 0; ic[t] = 0;
    __syncthreads();
    const int sA0 = tab[(size_t)b * NBC];
    const int sA1 = tab[(size_t)(b + 1) * NBC];
    const int dA0 = tab[(size_t)(NBK + b) * NBC] - E;
    const int dA1 = tab[(size_t)(NBK + b + 1) * NBC] - E;
    const int sl = sA1 - sA0, dl = dA1 - dA0;
    const int s0 = sA0 + (sl * s) / 4, s1 = sA0 + (sl * (s + 1)) / 4;
    const int d0 = dA0 + (dl * s) / 4, d1 = dA0 + (dl * (s + 1)) / 4;
    for (int i = s0 + t; i < s1; i += 256) atomicAdd(&oc[srecs[i]], 1);
    for (int i = d0 + t; i < d1; i += 256) atomicAdd(&ic[drecs[i] & 255], 1);
    __syncthreads();
    pdeg[(size_t)blockIdx.x * 256 + t] = (unsigned)oc[t] | ((unsigned)ic[t] << 16);
}

// ---------------- projection + degree fold (128-node tiles, reg prefetch) ----------------
// Double-buffer via registers: store pf(kt) -> LDS, issue global loads for
// kt+1, THEN compute kt. The vmcnt wait for the prefetch lands at the next
// iteration's ds_write, so global latency overlaps FMA+LDS of this tile.
__global__ __launch_bounds__(256) void k_gemm(const float* __restrict__ X,
                                              const float* __restrict__ W,
                                              const unsigned* __restrict__ pdeg,
                                              float* __restrict__ nd,
                                              unsigned short* __restrict__ Hb, int N) {
    __shared__ __align__(16) float lx[128 * 36];   // 18.4 KB
    __shared__ __align__(16) float lw[16 * 260];   // 16.6 KB
    __shared__ float lns[128];
    const int t = threadIdx.x;
    const int node0 = blockIdx.x * 128;

    if (t < 128) {   // degree fold (pdeg tiled per 256-node bucket)
        const int node = node0 + t;
        const int bk = node >> 8, w = node & 255;
        int od = 0, idg = 0;
#pragma unroll
        for (int s = 0; s < 4; ++s) {
            const unsigned p = pdeg[(size_t)(bk * 4 + s) * 256 + w];
            od  += (int)(p & 0xFFFFu);
            idg += (int)(p >> 16);
        }
        lns[t] = rsqrtf(fmaxf((float)od, 1.f));
        if (node < N) nd[node] = rsqrtf(fmaxf((float)idg, 1.f));
    }

    for (int i = t; i < 256 * 16; i += 256) {
        const int k = i >> 4, c = i & 15;
        lw[c * 260 + k] = W[i];
    }

    const int m  = t >> 2;         // 0..63
    const int cb = (t & 3) * 4;
    // each thread stages 4 float4: rows row0..row0+... f = t + 256*i
    const int srow = t >> 3, sc4 = (t & 7) * 4;   // per-i: row = srow + 32*i

    float4 pf[4];
#pragma unroll
    for (int i = 0; i < 4; ++i) {
        const int node = node0 + srow + 32 * i;
        pf[i] = (node < N) ? *(const float4*)&X[(size_t)node * 256 + sc4]
                           : float4{0.f, 0.f, 0.f, 0.f};
    }

    float4 acc[2][4];
#pragma unroll
    for (int j = 0; j < 2; ++j)
#pragma unroll
        for (int ci = 0; ci < 4; ++ci) acc[j][ci] = float4{0.f, 0.f, 0.f, 0.f};

    for (int kt = 0; kt < 8; ++kt) {
        __syncthreads();   // readers of previous tile done (and lw/lns staged on kt=0)
#pragma unroll
        for (int i = 0; i < 4; ++i)
            *(float4*)&lx[(srow + 32 * i) * 36 + sc4] = pf[i];
        if (kt < 7) {
            const int k0n = (kt + 1) * 32;
#pragma unroll
            for (int i = 0; i < 4; ++i) {
                const int node = node0 + srow + 32 * i;
                pf[i] = (node < N) ? *(const float4*)&X[(size_t)node * 256 + k0n + sc4]
                                   : float4{0.f, 0.f, 0.f, 0.f};
            }
        }
        __syncthreads();
        const int k0 = kt * 32;
#pragma unroll
        for (int kk = 0; kk < 32; kk += 4) {
            float4 wv[4], xv[2];
#pragma unroll
            for (int ci = 0; ci < 4; ++ci)
                wv[ci] = *(const float4*)&lw[(cb + ci) * 260 + k0 + kk];
#pragma unroll
            for (int j = 0; j < 2; ++j)
                xv[j] = *(const float4*)&lx[(m + 64 * j) * 36 + kk];
#pragma unroll
            for (int j = 0; j < 2; ++j)
#pragma unroll
                for (int ci = 0; ci < 4; ++ci) {
                    acc[j][ci].x += xv[j].x * wv[ci].x;
                    acc[j][ci].y += xv[j].y * wv[ci].y;
                    acc[j][ci].z += xv[j].z * wv[ci].z;
                    acc[j][ci].w += xv[j].w * wv[ci].w;
                }
        }
    }

#pragma unroll
    for (int j = 0; j < 2; ++j) {
        const int node = node0 + m + 64 * j;
        if (node < N) {
            const float norm = lns[m + 64 * j];
            ushort4 o;
            const float s0 = acc[j][0].x + acc[j][0].y + acc[j][0].z + acc[j][0].w;
            const float s1 = acc[j][1].x + acc[j][1].y + acc[j][1].z + acc[j][1].w;
            const float s2 = acc[j][2].x + acc[j][2].y + acc[j][2].z + acc[j][2].w;
            const float s3 = acc[j][3].x + acc[j][3].y + acc[j][3].z + acc[j][3].w;
            o.x = f2bf(s0 * norm); o.y = f2bf(s1 * norm);
            o.z = f2bf(s2 * norm); o.w = f2bf(s3 * norm);
            *(ushort4*)&Hb[(size_t)node * 16 + cb] = o;
        }
    }
}

// ---------------- per-bucket edge accumulation in REGISTERS ----------------
__global__ __launch_bounds__(256) void k_gaccum(const unsigned* __restrict__ drecs,
        const int* __restrict__ tab, const int* __restrict__ seg,
        const float* __restrict__ nd, const unsigned short* __restrict__ Hb,
        float* __restrict__ outagg, int N, int NBK, int NBC, int E, int G) {
    __shared__ float lnd[256];
    __shared__ int   lgi[256];
    __shared__ float lhist[256];
    __shared__ float wred[4 * 48];
    const int b = blockIdx.x >> 1, half = blockIdx.x & 1;
    const int t = threadIdx.x;
    const int node0 = b << 8;
    const int gf = seg[node0];
    lhist[t] = 0.f;
    const int node = node0 + t;
    if (node < N) {
        lnd[t] = nd[node];
        lgi[t] = seg[node] - gf;
    }
    __syncthreads();
    const int dA0 = tab[(size_t)(NBK + b) * NBC] - E;
    const int dA1 = tab[(size_t)(NBK + b + 1) * NBC] - E;
    const int mid = dA0 + ((dA1 - dA0) >> 1);
    const int i0 = half ? mid : dA0;
    const int i1 = half ? dA1 : mid;

    float a0[16], a1[16], a2[16];
#pragma unroll
    for (int j = 0; j < 16; ++j) { a0[j] = 0.f; a1[j] = 0.f; a2[j] = 0.f; }

    for (int i = i0 + t; i < i1; i += 256) {
        const unsigned r = drecs[i];
        const int dlow = r & 255;
        const int s = (int)(r >> 8);
        const float w = lnd[dlow];
        const int gi = lgi[dlow];
        const uint4* hp = (const uint4*)(Hb + (size_t)s * 16);
        const uint4 h0 = hp[0];
        const uint4 h1 = hp[1];
        if (gi < 3) {
            const float w0 = (gi == 0) ? w : 0.f;
            const float w1 = (gi == 1) ? w : 0.f;
            const float w2 = (gi == 2) ? w : 0.f;
#define ACC2(u, j0) { \
            float vlo = __uint_as_float((u) << 16); \
            float vhi = __uint_as_float((u) & 0xFFFF0000u); \
            a0[j0] += vlo * w0; a1[j0] += vlo * w1; a2[j0] += vlo * w2; \
            a0[j0+1] += vhi * w0; a1[j0+1] += vhi * w1; a2[j0+1] += vhi * w2; }
            ACC2(h0.x, 0) ACC2(h0.y, 2) ACC2(h0.z, 4) ACC2(h0.w, 6)
            ACC2(h1.x, 8) ACC2(h1.y, 10) ACC2(h1.z, 12) ACC2(h1.w, 14)
#undef ACC2
        } else {
            const unsigned hw[8] = {h0.x, h0.y, h0.z, h0.w, h1.x, h1.y, h1.z, h1.w};
            if (gi < 16) {
#pragma unroll
                for (int q = 0; q < 8; ++q) {
                    atomicAdd(&lhist[gi * 16 + 2 * q],     __uint_as_float(hw[q] << 16) * w);
                    atomicAdd(&lhist[gi * 16 + 2 * q + 1], __uint_as_float(hw[q] & 0xFFFF0000u) * w);
                }
            } else if (gf + gi < G) {
#pragma unroll
                for (int q = 0; q < 8; ++q) {
                    unsafeAtomicAdd(&outagg[(gf + gi) * 16 + 2 * q],     __uint_as_float(hw[q] << 16) * w);
                    unsafeAtomicAdd(&outagg[(gf + gi) * 16 + 2 * q + 1], __uint_as_float(hw[q] & 0xFFFF0000u) * w);
                }
            }
        }
    }

#pragma unroll
    for (int j = 0; j < 16; ++j) {
#pragma unroll
        for (int off = 32; off > 0; off >>= 1) {
            a0[j] += __shfl_down(a0[j], off, 64);
            a1[j] += __shfl_down(a1[j], off, 64);
            a2[j] += __shfl_down(a2[j], off, 64);
        }
    }
    const int wid = t >> 6, lane = t & 63;
    if (lane == 0) {
#pragma unroll
        for (int j = 0; j < 16; ++j) {
            wred[wid * 48 + j]      = a0[j];
            wred[wid * 48 + 16 + j] = a1[j];
            wred[wid * 48 + 32 + j] = a2[j];
        }
    }
    __syncthreads();
    if (t < 48) {
        const float v = wred[t] + wred[48 + t] + wred[96 + t] + wred[144 + t];
        const int g = gf + t / 16;
        if (v != 0.f && g < G) unsafeAtomicAdd(&outagg[g * 16 + (t & 15)], v);
    } else {
        const float v = lhist[t];
        const int g = gf + t / 16;
        if (v != 0.f && g < G) unsafeAtomicAdd(&outagg[g * 16 + (t & 15)], v);
    }
}

// ---------------- final: gcnt via binary search (seg sorted) ----------------
__global__ void k_final(const float* __restrict__ outagg, const int* __restrict__ seg,
                        const float* __restrict__ bias, float* __restrict__ out,
                        int N, int G) {
    int i = blockIdx.x * 256 + threadIdx.x;
    if (i < G * 16) {
        const int g = i >> 4;
        int lo = 0, hi = N;
        while (lo < hi) { int md = (lo + hi) >> 1; if (seg[md] < g) lo = md + 1; else hi = md; }
        const int a = lo; hi = N;
        while (lo < hi) { int md = (lo + hi) >> 1; if (seg[md] <= g) lo = md + 1; else hi = md; }
        const float cnt = (float)(lo - a);
        out[i] = outagg[i] / fmaxf(cnt, 1.f) + bias[i & 15];
    }
}

extern "C" void kernel_launch(void* const* d_in, const int* in_sizes, int n_in,
                              void* d_out, int out_size, void* d_ws, size_t ws_size,
                              hipStream_t stream) {
    const float* X  = (const float*)d_in[0];
    const float* W  = (const float*)d_in[1];
    const float* bb = (const float*)d_in[2];
    const int* esrc = (const int*)d_in[3];
    const int* edst = (const int*)d_in[4];
    const int* seg  = (const int*)d_in[5];
    const int N = in_sizes[5];                 // 100000
    const int E = in_sizes[3];                 // 3200000
    const int G = out_size / 16;               // 256
    const int NBK = (N + 255) >> 8;            // 391 (<=512 required)
    const int NBC = (((E + EVB - 1) / EVB) + 7) & ~7;   // 736 (x8 for swizzle)
    const int Ntab = 2 * NBK * NBC;            // 575552
    const int NBsc = (Ntab + 2047) / 2048;     // 282 scan blocks

    // ws layout (~20.3 MB; srecs/Hb aliased — srecs dead after k_degA)
    unsigned* drecs = (unsigned*)d_ws;                       // E u32 (12.8 MB)
    int* tab        = (int*)(drecs + (size_t)E);             // Ntab+1 ints (2.3 MB)
    int* bsum       = tab + (Ntab + 1);                      // NBsc (<=1024)
    float* nd       = (float*)(bsum + 1024);                 // N
    float* outagg   = nd + N;                                // G*16  <- memset
    unsigned* pdeg  = (unsigned*)(outagg + (size_t)G * 16);  // NBK*4*256 (1.6 MB)
    unsigned char* srecs = (unsigned char*)(pdeg + (size_t)NBK * 4 * 256); // E bytes \ alias
    unsigned short* Hb   = (unsigned short*)srecs;                          // N*16   / region

    hipMemsetAsync(outagg, 0, (size_t)G * 16 * 4, stream);

    k_count  <<<NBC, CTH, 0, stream>>>(esrc, edst, tab, E, NBK, NBC);
    k_scanA  <<<NBsc, 256, 0, stream>>>(tab, bsum, Ntab);
    k_scanB  <<<1, 256, 0, stream>>>(bsum, NBsc);
    k_scanC  <<<NBsc, 256, 0, stream>>>(tab, bsum, Ntab);
    k_scatter<<<NBC, CTH, 0, stream>>>(esrc, edst, tab, srecs, drecs, E, NBK, NBC);
    k_degA   <<<NBK * 4, 256, 0, stream>>>(srecs, drecs, tab, pdeg, NBK, NBC, E);
    k_gemm   <<<(N + 127) / 128, 256, 0, stream>>>(X, W, pdeg, nd, Hb, N);
    k_gaccum <<<NBK * 2, 256, 0, stream>>>(drecs, tab, seg, nd, Hb, outagg, N, NBK, NBC, E, G);
    k_final  <<<(G * 16 + 255) / 256, 256, 0, stream>>>(outagg, seg, bb, (float*)d_out, N, G);
}